// Round 4
// baseline (365.074 us; speedup 1.0000x reference)
//
#include <hip/hip_runtime.h>
#include <stdint.h>

#define NTOK   8192
#define DIM    1024
#define NEXP   8
#define MAXP   8192   // max token-expert pairs per expert

#define BM 128
#define BN 128

typedef float  f32x4  __attribute__((ext_vector_type(4)));
typedef __bf16 bf16x8 __attribute__((ext_vector_type(8)));

__device__ __forceinline__ unsigned short f32_to_bf16(float f) {
  union { float f; unsigned int u; } v; v.f = f;
  unsigned int u = v.u;
  unsigned int r = (u + 0x7FFFu + ((u >> 16) & 1u)) >> 16;
  return (unsigned short)r;
}

// ---------------------------------------------------------------------------
// We[e][d][h] fp32  ->  Wt[e][h][d] bf16  (B^T layout: contiguous in k=d)
// ---------------------------------------------------------------------------
__global__ __launch_bounds__(256) void transpose_we(
    const float* __restrict__ We, unsigned short* __restrict__ Wt) {
  __shared__ float tile[64][65];
  const int e  = blockIdx.z;
  const int d0 = blockIdx.y * 64;
  const int h0 = blockIdx.x * 64;
  const int t  = threadIdx.x;
  const int tx = t & 63, ty = t >> 6;
  const float* src = We + (size_t)e * DIM * DIM;
#pragma unroll
  for (int i = 0; i < 16; ++i) {
    int d = ty + i * 4;
    tile[d][tx] = src[(size_t)(d0 + d) * DIM + (h0 + tx)];
  }
  __syncthreads();
  unsigned short* dst = Wt + (size_t)e * DIM * DIM;
  const int tx2 = t & 31, ty8 = t >> 5;
#pragma unroll
  for (int i = 0; i < 8; ++i) {
    int h = ty8 + i * 8;
    int d = tx2 * 2;
    unsigned int pk = (unsigned int)f32_to_bf16(tile[d][h]) |
                      ((unsigned int)f32_to_bf16(tile[d + 1][h]) << 16);
    *(unsigned int*)&dst[(size_t)(h0 + h) * DIM + d0 + d] = pk;
  }
}

// ---------------------------------------------------------------------------
// Gate scores: fp64 accumulate, top-2, 2-way softmax. No atomics. Also x->bf16.
// ---------------------------------------------------------------------------
__global__ __launch_bounds__(256) void gate_score(
    const float* __restrict__ x, const float* __restrict__ Wg,
    const float* __restrict__ bg, unsigned short* __restrict__ Xbf,
    int* __restrict__ tok_ee, float2* __restrict__ tok_w) {
  const int wave = threadIdx.x >> 6;
  const int lane = threadIdx.x & 63;
  const int tok  = blockIdx.x * 4 + wave;

  const float* xr = x + (size_t)tok * DIM + lane * 16;
  float xs[16];
#pragma unroll
  for (int i = 0; i < 4; ++i) *(f32x4*)&xs[i * 4] = *(const f32x4*)(xr + i * 4);

  unsigned int packed[8];
#pragma unroll
  for (int i = 0; i < 8; ++i)
    packed[i] = (unsigned int)f32_to_bf16(xs[2 * i]) |
                ((unsigned int)f32_to_bf16(xs[2 * i + 1]) << 16);
  uint4* xb = (uint4*)(Xbf + (size_t)tok * DIM + lane * 16);
  xb[0] = make_uint4(packed[0], packed[1], packed[2], packed[3]);
  xb[1] = make_uint4(packed[4], packed[5], packed[6], packed[7]);

  double acc[8] = {0, 0, 0, 0, 0, 0, 0, 0};
  const float* wr = Wg + (size_t)(lane * 16) * NEXP;
#pragma unroll
  for (int i = 0; i < 16; ++i) {
    f32x4 wa = *(const f32x4*)(wr + i * 8);
    f32x4 wb = *(const f32x4*)(wr + i * 8 + 4);
    double xd = (double)xs[i];
    acc[0] += xd * (double)wa[0]; acc[1] += xd * (double)wa[1];
    acc[2] += xd * (double)wa[2]; acc[3] += xd * (double)wa[3];
    acc[4] += xd * (double)wb[0]; acc[5] += xd * (double)wb[1];
    acc[6] += xd * (double)wb[2]; acc[7] += xd * (double)wb[3];
  }
#pragma unroll
  for (int m = 1; m < 64; m <<= 1) {
#pragma unroll
    for (int e = 0; e < 8; ++e) acc[e] += __shfl_xor(acc[e], m, 64);
  }

  if (lane == 0) {
    float s[8];
#pragma unroll
    for (int e = 0; e < 8; ++e) s[e] = (float)acc[e] + bg[e];
    int i0 = 0; float v0 = s[0];
#pragma unroll
    for (int e = 1; e < 8; ++e) if (s[e] > v0) { v0 = s[e]; i0 = e; }
    int i1 = -1; float v1 = -3.4e38f;
#pragma unroll
    for (int e = 0; e < 8; ++e) if (e != i0 && s[e] > v1) { v1 = s[e]; i1 = e; }
    float t1 = expf(v1 - v0);
    float den = 1.0f + t1;
    tok_ee[tok] = i0 | (i1 << 8);
    tok_w[tok]  = make_float2(1.0f / den, t1 / den);
  }
}

// ---------------------------------------------------------------------------
// Deterministic compaction. pair_token[slot] = (tok<<1)|which.
// ---------------------------------------------------------------------------
__global__ __launch_bounds__(1024) void compact_kernel(
    const int* __restrict__ tok_ee, const float2* __restrict__ tok_w,
    int* __restrict__ counts, int* __restrict__ pair_token,
    float* __restrict__ pair_w) {
  __shared__ int wave_cnt[16][NEXP];
  __shared__ int wave_off[16][NEXP];
  __shared__ int base[NEXP];
  __shared__ int chunk_tot[NEXP];
  const int tid = threadIdx.x, wave = tid >> 6, lane = tid & 63;
  if (tid < NEXP) base[tid] = 0;
  __syncthreads();
  for (int c = 0; c < NTOK / 1024; ++c) {
    const int t = c * 1024 + tid;
    const int p = tok_ee[t];
    const int e0 = p & 255, e1 = (p >> 8) & 255;
    const float2 w = tok_w[t];
    int pre0 = 0, pre1 = 0;
    const unsigned long long below = (1ull << lane) - 1ull;
#pragma unroll
    for (int e = 0; e < NEXP; ++e) {
      unsigned long long m = __ballot(e0 == e || e1 == e);
      if (e0 == e) pre0 = __popcll(m & below);
      if (e1 == e) pre1 = __popcll(m & below);
      if (lane == 0) wave_cnt[wave][e] = __popcll(m);
    }
    __syncthreads();
    if (tid < NEXP) {
      int s = 0;
      for (int w2 = 0; w2 < 16; ++w2) {
        wave_off[w2][tid] = s;
        s += wave_cnt[w2][tid];
      }
      chunk_tot[tid] = s;
    }
    __syncthreads();
    const int s0 = base[e0] + wave_off[wave][e0] + pre0;
    const int s1 = base[e1] + wave_off[wave][e1] + pre1;
    pair_token[e0 * MAXP + s0] = (t << 1);     pair_w[e0 * MAXP + s0] = w.x;
    pair_token[e1 * MAXP + s1] = (t << 1) | 1; pair_w[e1 * MAXP + s1] = w.y;
    __syncthreads();
    if (tid < NEXP) base[tid] += chunk_tot[tid];
    __syncthreads();
  }
  if (tid < NEXP) counts[tid] = base[tid];
}

// ---------------------------------------------------------------------------
// Grouped GEMM — barrier-free, LDS-free. Each lane loads its MFMA fragments
// directly from global (16B contiguous per lane: row[fm], k=fq*8..+7), two
// register buffers, fully unrolled K so all offsets are immediates. The
// compiler pipelines loads(s+1) ahead of MFMAs(s) with fine-grained vmcnt.
// Waves pair-share fragments (2x block-level read redundancy) -> L1 absorbs.
// ---------------------------------------------------------------------------
__global__ __launch_bounds__(256) void moe_gemm(
    const unsigned short* __restrict__ Xbf, const unsigned short* __restrict__ Wt,
    const float* __restrict__ be, const int* __restrict__ counts,
    const int* __restrict__ pair_token, const float* __restrict__ pair_w,
    float* __restrict__ part, float* __restrict__ Y, int use_part) {
  const int e   = blockIdx.z;
  const int cnt = counts[e];
  const int m0  = blockIdx.y * BM;
  if (m0 >= cnt) return;
  const int n0  = blockIdx.x * BN;

  const int tid  = threadIdx.x;
  const int wave = tid >> 6;
  const int lane = tid & 63;
  const int fm   = lane & 15;
  const int fq   = lane >> 4;
  const int wm   = wave >> 1;
  const int wn   = wave & 1;

  // per-lane fragment base pointers (16B-aligned, contiguous in k)
  const unsigned short* pA[4];
  const unsigned short* pB[4];
#pragma unroll
  for (int i = 0; i < 4; ++i) {
    int gr = m0 + wm * 64 + i * 16 + fm;
    int tk = (gr < cnt) ? (pair_token[e * MAXP + gr] >> 1) : 0;
    pA[i] = Xbf + (size_t)tk * DIM + fq * 8;
  }
#pragma unroll
  for (int j = 0; j < 4; ++j) {
    int nr = n0 + wn * 64 + j * 16 + fm;
    pB[j] = Wt + (size_t)e * DIM * DIM + (size_t)nr * DIM + fq * 8;
  }

  f32x4 acc[4][4];
#pragma unroll
  for (int i = 0; i < 4; ++i)
#pragma unroll
    for (int j = 0; j < 4; ++j) { f32x4 z = {0.f, 0.f, 0.f, 0.f}; acc[i][j] = z; }

  bf16x8 af[2][4], bfr[2][4];
#pragma unroll
  for (int i = 0; i < 4; ++i) af[0][i] = *(const bf16x8*)(pA[i]);
#pragma unroll
  for (int j = 0; j < 4; ++j) bfr[0][j] = *(const bf16x8*)(pB[j]);

#pragma unroll
  for (int s = 0; s < DIM / 32; ++s) {
    const int cur = s & 1, nxt = cur ^ 1;
    if (s + 1 < DIM / 32) {
      const int ko = (s + 1) * 32;
#pragma unroll
      for (int i = 0; i < 4; ++i) af[nxt][i] = *(const bf16x8*)(pA[i] + ko);
#pragma unroll
      for (int j = 0; j < 4; ++j) bfr[nxt][j] = *(const bf16x8*)(pB[j] + ko);
    }
#pragma unroll
    for (int i = 0; i < 4; ++i)
#pragma unroll
      for (int j = 0; j < 4; ++j)
        acc[i][j] = __builtin_amdgcn_mfma_f32_16x16x32_bf16(af[cur][i],
                                                            bfr[cur][j],
                                                            acc[i][j], 0, 0, 0);
  }

  int   rowv[4][4];
  float wrow[4][4];
#pragma unroll
  for (int i = 0; i < 4; ++i)
#pragma unroll
    for (int r = 0; r < 4; ++r) {
      int gr = m0 + wm * 64 + i * 16 + fq * 4 + r;
      bool valid = gr < cnt;
      rowv[i][r] = valid ? pair_token[e * MAXP + gr] : -1;
      wrow[i][r] = valid ? pair_w[e * MAXP + gr] : 0.f;
    }
  if (use_part) {
#pragma unroll
    for (int j = 0; j < 4; ++j) {
      int col = n0 + wn * 64 + j * 16 + fm;
      float bev = be[e * DIM + col];
#pragma unroll
      for (int i = 0; i < 4; ++i)
#pragma unroll
        for (int r = 0; r < 4; ++r) {
          int v = rowv[i][r];
          if (v >= 0)
            part[(size_t)v * DIM + col] = wrow[i][r] * (acc[i][j][r] + bev);
        }
    }
  } else {
#pragma unroll
    for (int j = 0; j < 4; ++j) {
      int col = n0 + wn * 64 + j * 16 + fm;
      float bev = be[e * DIM + col];
#pragma unroll
      for (int i = 0; i < 4; ++i)
#pragma unroll
        for (int r = 0; r < 4; ++r) {
          int v = rowv[i][r];
          if (v >= 0)
            atomicAdd(Y + (size_t)(v >> 1) * DIM + col,
                      wrow[i][r] * (acc[i][j][r] + bev));
        }
    }
  }
}

// ---------------------------------------------------------------------------
// Y[t][d] = part[2t][d] + part[2t+1][d]  — fully coalesced float4.
// ---------------------------------------------------------------------------
__global__ __launch_bounds__(256) void reduce_pairs(
    const float* __restrict__ part, float* __restrict__ Y) {
  const int g = blockIdx.x * 256 + threadIdx.x;   // float4 index
  const int t = g >> 8;                           // DIM/4 = 256 per token
  const int o = (g & 255) * 4;
  const f32x4 a = *(const f32x4*)(part + (size_t)(2 * t) * DIM + o);
  const f32x4 b = *(const f32x4*)(part + (size_t)(2 * t + 1) * DIM + o);
  *(f32x4*)(Y + (size_t)t * DIM + o) = a + b;
}

// ---------------------------------------------------------------------------
extern "C" void kernel_launch(void* const* d_in, const int* in_sizes, int n_in,
                              void* d_out, int out_size, void* d_ws, size_t ws_size,
                              hipStream_t stream) {
  const float* x  = (const float*)d_in[0];
  const float* Wg = (const float*)d_in[1];
  const float* bg = (const float*)d_in[2];
  const float* We = (const float*)d_in[3];
  const float* be = (const float*)d_in[4];
  float* Y = (float*)d_out;

  const size_t MB = 1024 * 1024;
  char* ws = (char*)d_ws;
  unsigned short* Xbf = (unsigned short*)ws;                 // 16 MiB
  unsigned short* Wt  = (unsigned short*)(ws + 16 * MB);     // 16 MiB
  const size_t part_bytes = (size_t)NTOK * 2 * DIM * 4;      // 64 MiB
  const size_t need = 32 * MB + part_bytes + 1 * MB;
  const int use_part = ws_size >= need;
  float* part = (float*)(ws + 32 * MB);                      // 64 MiB if used
  char* p2 = ws + 32 * MB + (use_part ? part_bytes : 0);
  int*    counts     = (int*)p2;
  int*    pair_token = (int*)(p2 + 256);
  float*  pair_w     = (float*)(p2 + 256 + 262144);
  int*    tok_ee     = (int*)(p2 + 256 + 2 * 262144);
  float2* tok_w      = (float2*)(p2 + 256 + 2 * 262144 + 32768);

  if (!use_part)
    hipMemsetAsync(d_out, 0, (size_t)out_size * sizeof(float), stream);

  transpose_we<<<dim3(16, 16, NEXP), 256, 0, stream>>>(We, Wt);
  gate_score<<<NTOK / 4, 256, 0, stream>>>(x, Wg, bg, Xbf, tok_ee, tok_w);
  compact_kernel<<<1, 1024, 0, stream>>>(tok_ee, tok_w, counts, pair_token,
                                         pair_w);
  moe_gemm<<<dim3(8, NTOK / BM, NEXP), 256, 0, stream>>>(
      Xbf, Wt, be, counts, pair_token, pair_w, part, Y, use_part);
  if (use_part)
    reduce_pairs<<<NTOK * DIM / 4 / 256, 256, 0, stream>>>(part, Y);
}

// Round 5
// 241.540 us; speedup vs baseline: 1.5114x; 1.5114x over previous
//
#include <hip/hip_runtime.h>
#include <stdint.h>

#define NTOK   8192
#define DIM    1024
#define NEXP   8
#define MAXP   8192   // max token-expert pairs per expert

#define BM 128
#define BN 128
#define BK 32

typedef float  f32x4  __attribute__((ext_vector_type(4)));
typedef __bf16 bf16x8 __attribute__((ext_vector_type(8)));

typedef __attribute__((address_space(1))) const void* gas_ptr;
typedef __attribute__((address_space(3))) void*       las_ptr;

__device__ __forceinline__ unsigned short f32_to_bf16(float f) {
  union { float f; unsigned int u; } v; v.f = f;
  unsigned int u = v.u;
  unsigned int r = (u + 0x7FFFu + ((u >> 16) & 1u)) >> 16;
  return (unsigned short)r;
}

// ---------------------------------------------------------------------------
// Fused prep: blocks [0,2048) transpose We (fp32 [e][d][h] -> bf16 [e][h][d]);
// blocks [2048,4096) compute gate scores (fp64) + x->bf16. Saves one launch.
// ---------------------------------------------------------------------------
__global__ __launch_bounds__(256) void prep_kernel(
    const float* __restrict__ We, unsigned short* __restrict__ Wt,
    const float* __restrict__ x, const float* __restrict__ Wg,
    const float* __restrict__ bg, unsigned short* __restrict__ Xbf,
    int* __restrict__ tok_ee, float2* __restrict__ tok_w) {
  __shared__ float tile[64][65];
  const int bid = blockIdx.x;
  if (bid < 2048) {
    // ---- transpose We ----
    const int e  = bid >> 8;
    const int d0 = ((bid >> 4) & 15) * 64;
    const int h0 = (bid & 15) * 64;
    const int t  = threadIdx.x;
    const int tx = t & 63, ty = t >> 6;
    const float* src = We + (size_t)e * DIM * DIM;
#pragma unroll
    for (int i = 0; i < 16; ++i) {
      int d = ty + i * 4;
      tile[d][tx] = src[(size_t)(d0 + d) * DIM + (h0 + tx)];
    }
    __syncthreads();
    unsigned short* dst = Wt + (size_t)e * DIM * DIM;
    const int tx2 = t & 31, ty8 = t >> 5;
#pragma unroll
    for (int i = 0; i < 8; ++i) {
      int h = ty8 + i * 8;
      int d = tx2 * 2;
      unsigned int pk = (unsigned int)f32_to_bf16(tile[d][h]) |
                        ((unsigned int)f32_to_bf16(tile[d + 1][h]) << 16);
      *(unsigned int*)&dst[(size_t)(h0 + h) * DIM + d0 + d] = pk;
    }
    return;
  }
  // ---- gate scores ----
  const int blk  = bid - 2048;
  const int wave = threadIdx.x >> 6;
  const int lane = threadIdx.x & 63;
  const int tok  = blk * 4 + wave;

  const float* xr = x + (size_t)tok * DIM + lane * 16;
  float xs[16];
#pragma unroll
  for (int i = 0; i < 4; ++i) *(f32x4*)&xs[i * 4] = *(const f32x4*)(xr + i * 4);

  unsigned int packed[8];
#pragma unroll
  for (int i = 0; i < 8; ++i)
    packed[i] = (unsigned int)f32_to_bf16(xs[2 * i]) |
                ((unsigned int)f32_to_bf16(xs[2 * i + 1]) << 16);
  uint4* xb = (uint4*)(Xbf + (size_t)tok * DIM + lane * 16);
  xb[0] = make_uint4(packed[0], packed[1], packed[2], packed[3]);
  xb[1] = make_uint4(packed[4], packed[5], packed[6], packed[7]);

  double acc[8] = {0, 0, 0, 0, 0, 0, 0, 0};
  const float* wr = Wg + (size_t)(lane * 16) * NEXP;
#pragma unroll
  for (int i = 0; i < 16; ++i) {
    f32x4 wa = *(const f32x4*)(wr + i * 8);
    f32x4 wb = *(const f32x4*)(wr + i * 8 + 4);
    double xd = (double)xs[i];
    acc[0] += xd * (double)wa[0]; acc[1] += xd * (double)wa[1];
    acc[2] += xd * (double)wa[2]; acc[3] += xd * (double)wa[3];
    acc[4] += xd * (double)wb[0]; acc[5] += xd * (double)wb[1];
    acc[6] += xd * (double)wb[2]; acc[7] += xd * (double)wb[3];
  }
#pragma unroll
  for (int m = 1; m < 64; m <<= 1) {
#pragma unroll
    for (int e = 0; e < 8; ++e) acc[e] += __shfl_xor(acc[e], m, 64);
  }

  if (lane == 0) {
    float s[8];
#pragma unroll
    for (int e = 0; e < 8; ++e) s[e] = (float)acc[e] + bg[e];
    int i0 = 0; float v0 = s[0];
#pragma unroll
    for (int e = 1; e < 8; ++e) if (s[e] > v0) { v0 = s[e]; i0 = e; }
    int i1 = -1; float v1 = -3.4e38f;
#pragma unroll
    for (int e = 0; e < 8; ++e) if (e != i0 && s[e] > v1) { v1 = s[e]; i1 = e; }
    float t1 = expf(v1 - v0);
    float den = 1.0f + t1;
    tok_ee[tok] = i0 | (i1 << 8);
    tok_w[tok]  = make_float2(1.0f / den, t1 / den);
  }
}

// ---------------------------------------------------------------------------
// Deterministic compaction. pair_token[slot] = (tok<<1)|which.
// ---------------------------------------------------------------------------
__global__ __launch_bounds__(1024) void compact_kernel(
    const int* __restrict__ tok_ee, const float2* __restrict__ tok_w,
    int* __restrict__ counts, int* __restrict__ pair_token,
    float* __restrict__ pair_w) {
  __shared__ int wave_cnt[16][NEXP];
  __shared__ int wave_off[16][NEXP];
  __shared__ int base[NEXP];
  __shared__ int chunk_tot[NEXP];
  const int tid = threadIdx.x, wave = tid >> 6, lane = tid & 63;
  if (tid < NEXP) base[tid] = 0;
  __syncthreads();
  for (int c = 0; c < NTOK / 1024; ++c) {
    const int t = c * 1024 + tid;
    const int p = tok_ee[t];
    const int e0 = p & 255, e1 = (p >> 8) & 255;
    const float2 w = tok_w[t];
    int pre0 = 0, pre1 = 0;
    const unsigned long long below = (1ull << lane) - 1ull;
#pragma unroll
    for (int e = 0; e < NEXP; ++e) {
      unsigned long long m = __ballot(e0 == e || e1 == e);
      if (e0 == e) pre0 = __popcll(m & below);
      if (e1 == e) pre1 = __popcll(m & below);
      if (lane == 0) wave_cnt[wave][e] = __popcll(m);
    }
    __syncthreads();
    if (tid < NEXP) {
      int s = 0;
      for (int w2 = 0; w2 < 16; ++w2) {
        wave_off[w2][tid] = s;
        s += wave_cnt[w2][tid];
      }
      chunk_tot[tid] = s;
    }
    __syncthreads();
    const int s0 = base[e0] + wave_off[wave][e0] + pre0;
    const int s1 = base[e1] + wave_off[wave][e1] + pre1;
    pair_token[e0 * MAXP + s0] = (t << 1);     pair_w[e0 * MAXP + s0] = w.x;
    pair_token[e1 * MAXP + s1] = (t << 1) | 1; pair_w[e1 * MAXP + s1] = w.y;
    __syncthreads();
    if (tid < NEXP) base[tid] += chunk_tot[tid];
    __syncthreads();
  }
  if (tid < NEXP) counts[tid] = base[tid];
}

// ---------------------------------------------------------------------------
// Grouped GEMM, double-buffered LDS (R3 structure), 1D grid with expert ->
// XCD swizzle: e = id&7, so linear round-robin dispatch pins each expert's
// blocks to one XCD. Per-XCD L2 footprint: Wt[e] 2MB + its token rows ~4MB
// (vs 32MB unswizzled) -> staging drains become L2-latency, not HBM-latency.
// ---------------------------------------------------------------------------
__global__ __launch_bounds__(256) void moe_gemm(
    const unsigned short* __restrict__ Xbf, const unsigned short* __restrict__ Wt,
    const float* __restrict__ be, const int* __restrict__ counts,
    const int* __restrict__ pair_token, const float* __restrict__ pair_w,
    float* __restrict__ part, float* __restrict__ Y, int use_part) {
  const int id  = blockIdx.x;
  const int e   = id & 7;
  const int n0  = ((id >> 3) & 7) * BN;
  const int m0  = (id >> 6) * BM;
  const int cnt = counts[e];
  if (m0 >= cnt) return;

  __shared__ __align__(16) unsigned short As[2][BM * BK];
  __shared__ __align__(16) unsigned short Bs[2][BN * BK];

  const int tid  = threadIdx.x;
  const int wave = tid >> 6;
  const int lane = tid & 63;
  const int fm   = lane & 15;
  const int fq   = lane >> 4;
  const int wm   = wave >> 1;
  const int wn   = wave & 1;

  const int srow = wave * 32 + (lane >> 2);
  const int kc   = (lane & 3) * 8;
  const unsigned short* gA[2];
  const unsigned short* gB[2];
#pragma unroll
  for (int c = 0; c < 2; ++c) {
    int r  = srow + c * 16;
    int gr = m0 + r;
    int tk = (gr < cnt) ? (pair_token[e * MAXP + gr] >> 1) : 0;
    gA[c] = Xbf + (size_t)tk * DIM + kc;
    gB[c] = Wt + (size_t)e * DIM * DIM + (size_t)(n0 + r) * DIM + kc;
  }

#define STAGE(buf, koff)                                                      \
  {                                                                           \
    _Pragma("unroll") for (int c = 0; c < 2; ++c) {                           \
      __builtin_amdgcn_global_load_lds(                                       \
          (gas_ptr)(uintptr_t)(gA[c] + (koff)),                               \
          (las_ptr)(uintptr_t)(&As[buf][(wave * 2 + c) * 512]), 16, 0, 0);    \
      __builtin_amdgcn_global_load_lds(                                       \
          (gas_ptr)(uintptr_t)(gB[c] + (koff)),                               \
          (las_ptr)(uintptr_t)(&Bs[buf][(wave * 2 + c) * 512]), 16, 0, 0);    \
    }                                                                         \
  }

  f32x4 acc[4][4];
#pragma unroll
  for (int i = 0; i < 4; ++i)
#pragma unroll
    for (int j = 0; j < 4; ++j) { f32x4 z = {0.f, 0.f, 0.f, 0.f}; acc[i][j] = z; }

  STAGE(0, 0);
  int cur = 0;
  for (int k0 = 0; k0 < DIM; k0 += BK) {
    __syncthreads();           // drains buf[cur] loads (issued a full iter ago)
    if (k0 + BK < DIM) STAGE(cur ^ 1, k0 + BK);

    bf16x8 af[4], bfr[4];
#pragma unroll
    for (int i = 0; i < 4; ++i)
      af[i] = *(const bf16x8*)&As[cur][(wm * 64 + i * 16 + fm) * BK + fq * 8];
#pragma unroll
    for (int j = 0; j < 4; ++j)
      bfr[j] = *(const bf16x8*)&Bs[cur][(wn * 64 + j * 16 + fm) * BK + fq * 8];
#pragma unroll
    for (int i = 0; i < 4; ++i)
#pragma unroll
      for (int j = 0; j < 4; ++j)
        acc[i][j] = __builtin_amdgcn_mfma_f32_16x16x32_bf16(af[i], bfr[j],
                                                            acc[i][j], 0, 0, 0);
    cur ^= 1;
  }
#undef STAGE

  int   rowv[4][4];
  float wrow[4][4];
#pragma unroll
  for (int i = 0; i < 4; ++i)
#pragma unroll
    for (int r = 0; r < 4; ++r) {
      int gr = m0 + wm * 64 + i * 16 + fq * 4 + r;
      bool valid = gr < cnt;
      rowv[i][r] = valid ? pair_token[e * MAXP + gr] : -1;
      wrow[i][r] = valid ? pair_w[e * MAXP + gr] : 0.f;
    }
  if (use_part) {
#pragma unroll
    for (int j = 0; j < 4; ++j) {
      int col = n0 + wn * 64 + j * 16 + fm;
      float bev = be[e * DIM + col];
#pragma unroll
      for (int i = 0; i < 4; ++i)
#pragma unroll
        for (int r = 0; r < 4; ++r) {
          int v = rowv[i][r];
          if (v >= 0)
            part[(size_t)v * DIM + col] = wrow[i][r] * (acc[i][j][r] + bev);
        }
    }
  } else {
#pragma unroll
    for (int j = 0; j < 4; ++j) {
      int col = n0 + wn * 64 + j * 16 + fm;
      float bev = be[e * DIM + col];
#pragma unroll
      for (int i = 0; i < 4; ++i)
#pragma unroll
        for (int r = 0; r < 4; ++r) {
          int v = rowv[i][r];
          if (v >= 0)
            atomicAdd(Y + (size_t)(v >> 1) * DIM + col,
                      wrow[i][r] * (acc[i][j][r] + bev));
        }
    }
  }
}

// ---------------------------------------------------------------------------
// Y[t][d] = part[2t][d] + part[2t+1][d]  — fully coalesced float4.
// ---------------------------------------------------------------------------
__global__ __launch_bounds__(256) void reduce_pairs(
    const float* __restrict__ part, float* __restrict__ Y) {
  const int g = blockIdx.x * 256 + threadIdx.x;   // float4 index
  const int t = g >> 8;                           // DIM/4 = 256 per token
  const int o = (g & 255) * 4;
  const f32x4 a = *(const f32x4*)(part + (size_t)(2 * t) * DIM + o);
  const f32x4 b = *(const f32x4*)(part + (size_t)(2 * t + 1) * DIM + o);
  *(f32x4*)(Y + (size_t)t * DIM + o) = a + b;
}

// ---------------------------------------------------------------------------
extern "C" void kernel_launch(void* const* d_in, const int* in_sizes, int n_in,
                              void* d_out, int out_size, void* d_ws, size_t ws_size,
                              hipStream_t stream) {
  const float* x  = (const float*)d_in[0];
  const float* Wg = (const float*)d_in[1];
  const float* bg = (const float*)d_in[2];
  const float* We = (const float*)d_in[3];
  const float* be = (const float*)d_in[4];
  float* Y = (float*)d_out;

  const size_t MB = 1024 * 1024;
  char* ws = (char*)d_ws;
  unsigned short* Xbf = (unsigned short*)ws;                 // 16 MiB
  unsigned short* Wt  = (unsigned short*)(ws + 16 * MB);     // 16 MiB
  const size_t part_bytes = (size_t)NTOK * 2 * DIM * 4;      // 64 MiB
  const size_t need = 32 * MB + part_bytes + 1 * MB;
  const int use_part = ws_size >= need;
  float* part = (float*)(ws + 32 * MB);                      // 64 MiB if used
  char* p2 = ws + 32 * MB + (use_part ? part_bytes : 0);
  int*    counts     = (int*)p2;
  int*    pair_token = (int*)(p2 + 256);
  float*  pair_w     = (float*)(p2 + 256 + 262144);
  int*    tok_ee     = (int*)(p2 + 256 + 2 * 262144);
  float2* tok_w      = (float2*)(p2 + 256 + 2 * 262144 + 32768);

  if (!use_part)
    hipMemsetAsync(d_out, 0, (size_t)out_size * sizeof(float), stream);

  prep_kernel<<<4096, 256, 0, stream>>>(We, Wt, x, Wg, bg, Xbf, tok_ee, tok_w);
  compact_kernel<<<1, 1024, 0, stream>>>(tok_ee, tok_w, counts, pair_token,
                                         pair_w);
  moe_gemm<<<dim3(8 * 8 * (NTOK / BM)), 256, 0, stream>>>(
      Xbf, Wt, be, counts, pair_token, pair_w, part, Y, use_part);
  if (use_part)
    reduce_pairs<<<NTOK * DIM / 4 / 256, 256, 0, stream>>>(part, Y);
}